// Round 4
// baseline (229.891 us; speedup 1.0000x reference)
//
#include <hip/hip_runtime.h>
#include <hip/hip_bf16.h>

#define D     64    // feature dim == units
#define CH    4096  // edges per chunk (binning)
#define BKT   32    // nodes per bucket (aggregate)
#define PASS  1024  // edges staged per pass in aggregate
#define CAP   1024  // slab capacity per bucket (max observed ~600, 22-sigma margin)
#define CAPSH 10    // log2(CAP)

// ---------------------------------------------------------------------------
// front: blocks [0,NC): bin chunk c's edges into per-bucket slabs via global
// atomicAdd (device scope).  Blocks [NC, NC+gemmTiles): Z = emb @ W (bf16).
// rec.x = src(16) | dl(5)<<16   (N < 65536).
// ---------------------------------------------------------------------------
__global__ __launch_bounds__(256) void front(
    const float* __restrict__ emb,
    const float* __restrict__ W,
    __hip_bfloat16* __restrict__ Zb,
    const int*   __restrict__ src,
    const int*   __restrict__ dst,
    const float* __restrict__ w,
    int*         __restrict__ gcnt,   // [NB], pre-zeroed by memset
    int2*        __restrict__ csr,    // [NB * CAP] slabs
    int N, int E, int NC)
{
    __shared__ float At[4096];   // 16 KB, GEMM branch only

    const int t = threadIdx.x;

    if ((int)blockIdx.x < NC) {
        // ---- bin branch: 16 edges/thread, vector loads, atomic slab fill --
        const int c   = blockIdx.x;
        const int e0  = c * CH;
        const int cnt = min(CH, E - e0);   // multiple of 4 (E%4==0)
        const int4*   s4p = reinterpret_cast<const int4*>(src + e0);
        const int4*   d4p = reinterpret_cast<const int4*>(dst + e0);
        const float4* w4p = reinterpret_cast<const float4*>(w + e0);
#pragma unroll
        for (int i = 0; i < 4; ++i) {
            int g = i * 256 + t;
            if (g * 4 < cnt) {
                int4   s4 = s4p[g];
                int4   d4 = d4p[g];
                float4 w4 = w4p[g];
                int b0 = d4.x >> 5, b1 = d4.y >> 5, b2 = d4.z >> 5, b3 = d4.w >> 5;
                int p0 = atomicAdd(&gcnt[b0], 1);
                int p1 = atomicAdd(&gcnt[b1], 1);
                int p2 = atomicAdd(&gcnt[b2], 1);
                int p3 = atomicAdd(&gcnt[b3], 1);
                csr[(b0 << CAPSH) + p0] = make_int2(s4.x | ((d4.x & 31) << 16), __float_as_int(w4.x));
                csr[(b1 << CAPSH) + p1] = make_int2(s4.y | ((d4.y & 31) << 16), __float_as_int(w4.y));
                csr[(b2 << CAPSH) + p2] = make_int2(s4.z | ((d4.z & 31) << 16), __float_as_int(w4.z));
                csr[(b3 << CAPSH) + p3] = make_int2(s4.w | ((d4.w & 31) << 16), __float_as_int(w4.w));
            }
        }
        return;
    }

    // ---- GEMM branch: tile (blockIdx.x - NC), proven R0 body --------------
    const int row0 = ((int)blockIdx.x - NC) * 64;
    const int lane = t & 63;
    const int wave = t >> 6;

    float wcol[D];
#pragma unroll
    for (int k = 0; k < D; ++k) wcol[k] = W[k * D + lane];

    for (int i = t; i < 1024; i += 256) {
        int r = i >> 4, gr = row0 + r;
        float4 v = (gr < N)
            ? reinterpret_cast<const float4*>(emb)[(size_t)gr * 16 + (i & 15)]
            : float4{0.f, 0.f, 0.f, 0.f};
        reinterpret_cast<float4*>(At)[i] = v;
    }
    __syncthreads();

    for (int rr = 0; rr < 16; ++rr) {
        int r = wave * 16 + rr, gr = row0 + r;
        if (gr >= N) break;
        const float4* arow = reinterpret_cast<const float4*>(At + r * D);
        float acc = 0.f;
#pragma unroll
        for (int k4 = 0; k4 < 16; ++k4) {
            float4 a = arow[k4];
            acc = fmaf(a.x, wcol[4 * k4 + 0], acc);
            acc = fmaf(a.y, wcol[4 * k4 + 1], acc);
            acc = fmaf(a.z, wcol[4 * k4 + 2], acc);
            acc = fmaf(a.w, wcol[4 * k4 + 3], acc);
        }
        Zb[(size_t)gr * D + lane] = __float2bfloat16(acc);
    }
}

// ---------------------------------------------------------------------------
// aggregate: one block per 32-node bucket; slab bounds = [b*CAP, b*CAP+gcnt[b]).
// Sort pass edges by node in LDS (int atomics + shfl scan), then register-
// gather with 3-deep per-slot prefetch.  Body identical to R0 best.
// ---------------------------------------------------------------------------
__global__ __launch_bounds__(256) void aggregate(
    const __hip_bfloat16* __restrict__ Zb,
    const int2* __restrict__ csr,
    const int*  __restrict__ gcnt,
    float*      __restrict__ out,
    int N, int NB)
{
    __shared__ int2 srec[PASS];   // 8 KB
    __shared__ int  hist[BKT];
    __shared__ int  nbase[BKT + 1];

    const int t = threadIdx.x;
    const int b = blockIdx.x;

    const int bStart = b << CAPSH;
    const int bEnd   = bStart + gcnt[b];

    const int wv = t >> 6, lane = t & 63, slot = lane >> 3, q = lane & 7;
    const int4* Zq = reinterpret_cast<const int4*>(Zb);   // bf16 row = 8 int4

    float4 alo[8], ahi[8];
#pragma unroll
    for (int r = 0; r < 8; ++r) { alo[r] = float4{0,0,0,0}; ahi[r] = float4{0,0,0,0}; }

#define FMA8(LO, HI, WW, ZZ)                                                     \
    do {                                                                         \
        (LO).x = fmaf((WW), __uint_as_float((unsigned)(ZZ).x << 16),        (LO).x); \
        (LO).y = fmaf((WW), __uint_as_float((unsigned)(ZZ).x & 0xFFFF0000u),(LO).y); \
        (LO).z = fmaf((WW), __uint_as_float((unsigned)(ZZ).y << 16),        (LO).z); \
        (LO).w = fmaf((WW), __uint_as_float((unsigned)(ZZ).y & 0xFFFF0000u),(LO).w); \
        (HI).x = fmaf((WW), __uint_as_float((unsigned)(ZZ).z << 16),        (HI).x); \
        (HI).y = fmaf((WW), __uint_as_float((unsigned)(ZZ).z & 0xFFFF0000u),(HI).y); \
        (HI).z = fmaf((WW), __uint_as_float((unsigned)(ZZ).w << 16),        (HI).z); \
        (HI).w = fmaf((WW), __uint_as_float((unsigned)(ZZ).w & 0xFFFF0000u),(HI).w); \
    } while (0)

    for (int cur = bStart; cur < bEnd; cur += PASS) {
        const int cnt = min(PASS, bEnd - cur);
        if (t < BKT) hist[t] = 0;
        __syncthreads();

        int2 myrec[4]; int mypos[4];
#pragma unroll
        for (int k = 0; k < 4; ++k) {
            int j = k * 256 + t;
            if (j < cnt) {
                int2 r2 = csr[cur + j];
                myrec[k] = r2;
                mypos[k] = atomicAdd(&hist[(r2.x >> 16) & (BKT - 1)], 1);
            } else mypos[k] = -1;
        }
        __syncthreads();

        if (t < BKT) {
            int v = hist[t], x = v;
            for (int off = 1; off < BKT; off <<= 1) {
                int y = __shfl_up(x, off, 64);
                if (t >= off) x += y;
            }
            nbase[t] = x - v;
            if (t == BKT - 1) nbase[BKT] = x;
        }
        __syncthreads();

#pragma unroll
        for (int k = 0; k < 4; ++k) {
            if (mypos[k] >= 0)
                srec[nbase[(myrec[k].x >> 16) & (BKT - 1)] + mypos[k]] = myrec[k];
        }
        __syncthreads();

        // gather: wave wv owns nodes [wv*8, wv*8+8), 3-deep prefetched
        for (int r = 0; r < 8; ++r) {
            const int nl = wv * 8 + r;
            const int jb = nbase[nl] + slot;
            const int je = nbase[nl + 1];
            const int j1 = jb + 8, j2 = jb + 16;
            int2 e0 = make_int2(0, 0), e1 = make_int2(0, 0), e2 = make_int2(0, 0);
            if (jb < je) e0 = srec[jb];
            if (j1 < je) e1 = srec[j1];
            if (j2 < je) e2 = srec[j2];
            int4 z0 = make_int4(0,0,0,0), z1 = make_int4(0,0,0,0), z2 = make_int4(0,0,0,0);
            if (jb < je) z0 = Zq[(size_t)(e0.x & 0xFFFF) * 8 + q];
            if (j1 < je) z1 = Zq[(size_t)(e1.x & 0xFFFF) * 8 + q];
            if (j2 < je) z2 = Zq[(size_t)(e2.x & 0xFFFF) * 8 + q];
            FMA8(alo[r], ahi[r], __int_as_float(e0.y), z0);
            FMA8(alo[r], ahi[r], __int_as_float(e1.y), z1);
            FMA8(alo[r], ahi[r], __int_as_float(e2.y), z2);
            for (int j = j2 + 8; j < je; j += 8) {    // tail (deg > 24)
                int2 e = srec[j];
                int4 zz = Zq[(size_t)(e.x & 0xFFFF) * 8 + q];
                FMA8(alo[r], ahi[r], __int_as_float(e.y), zz);
            }
        }
        __syncthreads();
    }

    // reduce the 8 slots + store (8 lanes x 32 B = coalesced 256 B row)
    const int node0 = b * BKT + wv * 8;
#pragma unroll
    for (int r = 0; r < 8; ++r) {
        float4 lo = alo[r], hi = ahi[r];
#pragma unroll
        for (int off = 32; off >= 8; off >>= 1) {
            lo.x += __shfl_down(lo.x, off, 64);
            lo.y += __shfl_down(lo.y, off, 64);
            lo.z += __shfl_down(lo.z, off, 64);
            lo.w += __shfl_down(lo.w, off, 64);
            hi.x += __shfl_down(hi.x, off, 64);
            hi.y += __shfl_down(hi.y, off, 64);
            hi.z += __shfl_down(hi.z, off, 64);
            hi.w += __shfl_down(hi.w, off, 64);
        }
        int node = node0 + r;
        if (lane < 8 && node < N) {
            float4 o0, o1;
            o0.x = fmaxf(lo.x, 0.f); o0.y = fmaxf(lo.y, 0.f);
            o0.z = fmaxf(lo.z, 0.f); o0.w = fmaxf(lo.w, 0.f);
            o1.x = fmaxf(hi.x, 0.f); o1.y = fmaxf(hi.y, 0.f);
            o1.z = fmaxf(hi.z, 0.f); o1.w = fmaxf(hi.w, 0.f);
            float4* orow = reinterpret_cast<float4*>(out) + (size_t)node * 16 + lane * 2;
            orow[0] = o0;
            orow[1] = o1;
        }
    }
#undef FMA8
}

// ---------------------------------------------------------------------------
extern "C" void kernel_launch(void* const* d_in, const int* in_sizes, int n_in,
                              void* d_out, int out_size, void* d_ws, size_t ws_size,
                              hipStream_t stream)
{
    const float* emb  = (const float*)d_in[0];  // [N, 64]
    const int*   esrc = (const int*)  d_in[1];  // [E]
    const int*   edst = (const int*)  d_in[2];  // [E]
    const float* ew   = (const float*)d_in[3];  // [E]
    const float* W    = (const float*)d_in[4];  // [64, 64]
    float*       out  = (float*)d_out;          // [N, 64]

    const int N = in_sizes[0] / D;
    const int E = in_sizes[1];

    const int NB        = (N + BKT - 1) / BKT;   // 1563 buckets
    const int NC        = (E + CH - 1) / CH;     // 196 chunks
    const int gemmTiles = (N + 63) / 64;         // 782

    // Workspace (~19.3 MB), all segments 16 B aligned.
    char* p = (char*)d_ws;
    __hip_bfloat16* Zb = (__hip_bfloat16*)p;  p += (size_t)N * D * 2;      // 6.4 MB
    int*  gcnt = (int*)p;                     p += (size_t)((NB + 3) & ~3) * 4;
    int2* csr  = (int2*)p;                    // NB * CAP * 8 = 12.8 MB

    hipMemsetAsync(gcnt, 0, (size_t)NB * sizeof(int), stream);

    front<<<NC + gemmTiles, 256, 0, stream>>>(
        emb, W, Zb, esrc, edst, ew, gcnt, csr, N, E, NC);

    aggregate<<<NB, 256, 0, stream>>>(
        Zb, csr, gcnt, out, N, NB);
}

// Round 5
// 144.474 us; speedup vs baseline: 1.5912x; 1.5912x over previous
//
#include <hip/hip_runtime.h>
#include <hip/hip_bf16.h>

#define D     64    // feature dim == units
#define CH    4096  // edges per chunk (bin/stage)
#define BKT   32    // nodes per bucket (aggregate)
#define PASS  1024  // edges staged per pass in aggregate
#define CAP   1024  // slab capacity per bucket (Poisson(512), ~22-sigma margin)
#define CAPSH 10    // log2(CAP)

// ---------------------------------------------------------------------------
// front: blocks [0,NC): per-chunk LDS bucket-sort (R0-K3 body) + ONE global
// atomicAdd per (block,bucket) reserving slab space in csr — replaces the
// hist/scan/scan/offsets pipeline entirely.  Blocks [NC,NC+gemmTiles):
// Z = emb @ W (bf16 out), proven R0 tile.
// rec.x = src(16) | dl(5)<<16 | bkt(11)<<21   (N < 65536, NB < 2048).
// ---------------------------------------------------------------------------
__global__ __launch_bounds__(256) void front(
    const float* __restrict__ emb,
    const float* __restrict__ W,
    __hip_bfloat16* __restrict__ Zb,
    const int*   __restrict__ src,
    const int*   __restrict__ dst,
    const float* __restrict__ w,
    int*         __restrict__ gcnt,   // [NB], pre-zeroed by memset
    int2*        __restrict__ csr,    // [NB * CAP] slabs
    int N, int E, int NB, int NC)
{
    __shared__ int2 rec[CH];       // 32 KB (GEMM branch aliases 16 KB as At)
    __shared__ int  lcnt[1568];    // 6.3 KB
    __shared__ int  sh[256];       // 1 KB

    const int t = threadIdx.x;

    if ((int)blockIdx.x < NC) {
        const int c   = blockIdx.x;
        const int e0  = c * CH;
        const int cnt = min(CH, E - e0);   // multiple of 4 (E%4==0)

        for (int b = t; b < NB; b += 256) lcnt[b] = 0;
        __syncthreads();

        // ---- load + count-with-return (16 edges/thread, vector loads) ----
        int2 myrec[16]; int mypos[16];
        const int4*   s4p = reinterpret_cast<const int4*>(src + e0);
        const int4*   d4p = reinterpret_cast<const int4*>(dst + e0);
        const float4* w4p = reinterpret_cast<const float4*>(w + e0);
#pragma unroll
        for (int i = 0; i < 4; ++i) {
            int g = i * 256 + t;
            if (g * 4 < cnt) {
                int4   s4 = s4p[g];
                int4   d4 = d4p[g];
                float4 w4 = w4p[g];
                int b0 = d4.x >> 5, b1 = d4.y >> 5, b2 = d4.z >> 5, b3 = d4.w >> 5;
                myrec[4*i+0] = make_int2(s4.x | ((d4.x & 31) << 16) | (b0 << 21), __float_as_int(w4.x));
                myrec[4*i+1] = make_int2(s4.y | ((d4.y & 31) << 16) | (b1 << 21), __float_as_int(w4.y));
                myrec[4*i+2] = make_int2(s4.z | ((d4.z & 31) << 16) | (b2 << 21), __float_as_int(w4.z));
                myrec[4*i+3] = make_int2(s4.w | ((d4.w & 31) << 16) | (b3 << 21), __float_as_int(w4.w));
                mypos[4*i+0] = atomicAdd(&lcnt[b0], 1);
                mypos[4*i+1] = atomicAdd(&lcnt[b1], 1);
                mypos[4*i+2] = atomicAdd(&lcnt[b2], 1);
                mypos[4*i+3] = atomicAdd(&lcnt[b3], 1);
            } else {
#pragma unroll
                for (int k = 0; k < 4; ++k) mypos[4*i+k] = -1;
            }
        }
        __syncthreads();

        // ---- per-bucket counts; ISSUE slab reservation atomics early -----
        // (their ~700cy latency hides under the local scan + staging below)
        int hv[7], ps[7], gbase[7];
        const int hbase = t * 7;
#pragma unroll
        for (int k = 0; k < 7; ++k) {
            int b = hbase + k;
            hv[k] = (b < NB) ? lcnt[b] : 0;
        }
#pragma unroll
        for (int k = 0; k < 7; ++k)
            gbase[k] = (hv[k] > 0) ? atomicAdd(&gcnt[hbase + k], hv[k]) : 0;

        // ---- local exclusive scan of counts (for LDS staging layout) -----
        int s = 0;
#pragma unroll
        for (int k = 0; k < 7; ++k) { ps[k] = s; s += hv[k]; }
        sh[t] = s;
        __syncthreads();
        for (int off = 1; off < 256; off <<= 1) {
            int x = (t >= off) ? sh[t - off] : 0;
            __syncthreads();
            sh[t] += x;
            __syncthreads();
        }
        const int hexcl = sh[t] - s;
        __syncthreads();                       // all reads of lcnt done
#pragma unroll
        for (int k = 0; k < 7; ++k) {
            int b = hbase + k;
            if (b < NB) lcnt[b] = hexcl + ps[k];   // localBase
        }
        __syncthreads();

        // ---- stage records sorted by bucket ------------------------------
#pragma unroll
        for (int k = 0; k < 16; ++k) {
            if (mypos[k] >= 0)
                rec[lcnt[(unsigned)myrec[k].x >> 21] + mypos[k]] = myrec[k];
        }
        __syncthreads();

        // ---- lcnt[b] := slabStart + gbase - localBase --------------------
#pragma unroll
        for (int k = 0; k < 7; ++k) {
            int b = hbase + k;
            if (b < NB) lcnt[b] = (b << CAPSH) + gbase[k] - (hexcl + ps[k]);
        }
        __syncthreads();

        // ---- bulk write: run of bucket b lands at its reserved slab slot -
        for (int j = t; j < cnt; j += 256) {
            int2 rj = rec[j];
            csr[j + lcnt[(unsigned)rj.x >> 21]] = rj;
        }
        return;
    }

    // ---- GEMM branch: tile (blockIdx.x - NC), proven R0 body --------------
    float* At = (float*)rec;   // 16 KB alias
    const int row0 = ((int)blockIdx.x - NC) * 64;
    const int lane = t & 63;
    const int wave = t >> 6;

    float wcol[D];
#pragma unroll
    for (int k = 0; k < D; ++k) wcol[k] = W[k * D + lane];

    for (int i = t; i < 1024; i += 256) {
        int r = i >> 4, gr = row0 + r;
        float4 v = (gr < N)
            ? reinterpret_cast<const float4*>(emb)[(size_t)gr * 16 + (i & 15)]
            : float4{0.f, 0.f, 0.f, 0.f};
        reinterpret_cast<float4*>(At)[i] = v;
    }
    __syncthreads();

    for (int rr = 0; rr < 16; ++rr) {
        int r = wave * 16 + rr, gr = row0 + r;
        if (gr >= N) break;
        const float4* arow = reinterpret_cast<const float4*>(At + r * D);
        float acc = 0.f;
#pragma unroll
        for (int k4 = 0; k4 < 16; ++k4) {
            float4 a = arow[k4];
            acc = fmaf(a.x, wcol[4 * k4 + 0], acc);
            acc = fmaf(a.y, wcol[4 * k4 + 1], acc);
            acc = fmaf(a.z, wcol[4 * k4 + 2], acc);
            acc = fmaf(a.w, wcol[4 * k4 + 3], acc);
        }
        Zb[(size_t)gr * D + lane] = __float2bfloat16(acc);
    }
}

// ---------------------------------------------------------------------------
// aggregate: one block per 32-node bucket; slab bounds [b*CAP, b*CAP+gcnt[b]).
// Body verbatim from R4 (harness-verified).  LDS sort by node, then register
// gather with 3-deep per-slot prefetch.
// ---------------------------------------------------------------------------
__global__ __launch_bounds__(256) void aggregate(
    const __hip_bfloat16* __restrict__ Zb,
    const int2* __restrict__ csr,
    const int*  __restrict__ gcnt,
    float*      __restrict__ out,
    int N, int NB)
{
    __shared__ int2 srec[PASS];   // 8 KB
    __shared__ int  hist[BKT];
    __shared__ int  nbase[BKT + 1];

    const int t = threadIdx.x;
    const int b = blockIdx.x;

    const int bStart = b << CAPSH;
    const int bEnd   = bStart + gcnt[b];

    const int wv = t >> 6, lane = t & 63, slot = lane >> 3, q = lane & 7;
    const int4* Zq = reinterpret_cast<const int4*>(Zb);   // bf16 row = 8 int4

    float4 alo[8], ahi[8];
#pragma unroll
    for (int r = 0; r < 8; ++r) { alo[r] = float4{0,0,0,0}; ahi[r] = float4{0,0,0,0}; }

#define FMA8(LO, HI, WW, ZZ)                                                     \
    do {                                                                         \
        (LO).x = fmaf((WW), __uint_as_float((unsigned)(ZZ).x << 16),        (LO).x); \
        (LO).y = fmaf((WW), __uint_as_float((unsigned)(ZZ).x & 0xFFFF0000u),(LO).y); \
        (LO).z = fmaf((WW), __uint_as_float((unsigned)(ZZ).y << 16),        (LO).z); \
        (LO).w = fmaf((WW), __uint_as_float((unsigned)(ZZ).y & 0xFFFF0000u),(LO).w); \
        (HI).x = fmaf((WW), __uint_as_float((unsigned)(ZZ).z << 16),        (HI).x); \
        (HI).y = fmaf((WW), __uint_as_float((unsigned)(ZZ).z & 0xFFFF0000u),(HI).y); \
        (HI).z = fmaf((WW), __uint_as_float((unsigned)(ZZ).w << 16),        (HI).z); \
        (HI).w = fmaf((WW), __uint_as_float((unsigned)(ZZ).w & 0xFFFF0000u),(HI).w); \
    } while (0)

    for (int cur = bStart; cur < bEnd; cur += PASS) {
        const int cnt = min(PASS, bEnd - cur);
        if (t < BKT) hist[t] = 0;
        __syncthreads();

        int2 myrec[4]; int mypos[4];
#pragma unroll
        for (int k = 0; k < 4; ++k) {
            int j = k * 256 + t;
            if (j < cnt) {
                int2 r2 = csr[cur + j];
                myrec[k] = r2;
                mypos[k] = atomicAdd(&hist[(r2.x >> 16) & (BKT - 1)], 1);
            } else mypos[k] = -1;
        }
        __syncthreads();

        if (t < BKT) {
            int v = hist[t], x = v;
            for (int off = 1; off < BKT; off <<= 1) {
                int y = __shfl_up(x, off, 64);
                if (t >= off) x += y;
            }
            nbase[t] = x - v;
            if (t == BKT - 1) nbase[BKT] = x;
        }
        __syncthreads();

#pragma unroll
        for (int k = 0; k < 4; ++k) {
            if (mypos[k] >= 0)
                srec[nbase[(myrec[k].x >> 16) & (BKT - 1)] + mypos[k]] = myrec[k];
        }
        __syncthreads();

        // gather: wave wv owns nodes [wv*8, wv*8+8), 3-deep prefetched
        for (int r = 0; r < 8; ++r) {
            const int nl = wv * 8 + r;
            const int jb = nbase[nl] + slot;
            const int je = nbase[nl + 1];
            const int j1 = jb + 8, j2 = jb + 16;
            int2 e0 = make_int2(0, 0), e1 = make_int2(0, 0), e2 = make_int2(0, 0);
            if (jb < je) e0 = srec[jb];
            if (j1 < je) e1 = srec[j1];
            if (j2 < je) e2 = srec[j2];
            int4 z0 = make_int4(0,0,0,0), z1 = make_int4(0,0,0,0), z2 = make_int4(0,0,0,0);
            if (jb < je) z0 = Zq[(size_t)(e0.x & 0xFFFF) * 8 + q];
            if (j1 < je) z1 = Zq[(size_t)(e1.x & 0xFFFF) * 8 + q];
            if (j2 < je) z2 = Zq[(size_t)(e2.x & 0xFFFF) * 8 + q];
            FMA8(alo[r], ahi[r], __int_as_float(e0.y), z0);
            FMA8(alo[r], ahi[r], __int_as_float(e1.y), z1);
            FMA8(alo[r], ahi[r], __int_as_float(e2.y), z2);
            for (int j = j2 + 8; j < je; j += 8) {    // tail (deg > 24)
                int2 e = srec[j];
                int4 zz = Zq[(size_t)(e.x & 0xFFFF) * 8 + q];
                FMA8(alo[r], ahi[r], __int_as_float(e.y), zz);
            }
        }
        __syncthreads();
    }

    // reduce the 8 slots + store (8 lanes x 32 B = coalesced 256 B row)
    const int node0 = b * BKT + wv * 8;
#pragma unroll
    for (int r = 0; r < 8; ++r) {
        float4 lo = alo[r], hi = ahi[r];
#pragma unroll
        for (int off = 32; off >= 8; off >>= 1) {
            lo.x += __shfl_down(lo.x, off, 64);
            lo.y += __shfl_down(lo.y, off, 64);
            lo.z += __shfl_down(lo.z, off, 64);
            lo.w += __shfl_down(lo.w, off, 64);
            hi.x += __shfl_down(hi.x, off, 64);
            hi.y += __shfl_down(hi.y, off, 64);
            hi.z += __shfl_down(hi.z, off, 64);
            hi.w += __shfl_down(hi.w, off, 64);
        }
        int node = node0 + r;
        if (lane < 8 && node < N) {
            float4 o0, o1;
            o0.x = fmaxf(lo.x, 0.f); o0.y = fmaxf(lo.y, 0.f);
            o0.z = fmaxf(lo.z, 0.f); o0.w = fmaxf(lo.w, 0.f);
            o1.x = fmaxf(hi.x, 0.f); o1.y = fmaxf(hi.y, 0.f);
            o1.z = fmaxf(hi.z, 0.f); o1.w = fmaxf(hi.w, 0.f);
            float4* orow = reinterpret_cast<float4*>(out) + (size_t)node * 16 + lane * 2;
            orow[0] = o0;
            orow[1] = o1;
        }
    }
#undef FMA8
}

// ---------------------------------------------------------------------------
extern "C" void kernel_launch(void* const* d_in, const int* in_sizes, int n_in,
                              void* d_out, int out_size, void* d_ws, size_t ws_size,
                              hipStream_t stream)
{
    const float* emb  = (const float*)d_in[0];  // [N, 64]
    const int*   esrc = (const int*)  d_in[1];  // [E]
    const int*   edst = (const int*)  d_in[2];  // [E]
    const float* ew   = (const float*)d_in[3];  // [E]
    const float* W    = (const float*)d_in[4];  // [64, 64]
    float*       out  = (float*)d_out;          // [N, 64]

    const int N = in_sizes[0] / D;
    const int E = in_sizes[1];

    const int NB        = (N + BKT - 1) / BKT;   // 1563 buckets
    const int NC        = (E + CH - 1) / CH;     // 196 chunks
    const int gemmTiles = (N + 63) / 64;         // 782

    // Workspace (~19.3 MB), all segments 16 B aligned.
    char* p = (char*)d_ws;
    __hip_bfloat16* Zb = (__hip_bfloat16*)p;  p += (size_t)N * D * 2;      // 6.4 MB
    int*  gcnt = (int*)p;                     p += (size_t)((NB + 3) & ~3) * 4;
    int2* csr  = (int2*)p;                    // NB * CAP * 8 = 12.8 MB

    hipMemsetAsync(gcnt, 0, (size_t)NB * sizeof(int), stream);

    front<<<NC + gemmTiles, 256, 0, stream>>>(
        emb, W, Zb, esrc, edst, ew, gcnt, csr, N, E, NB, NC);

    aggregate<<<NB, 256, 0, stream>>>(
        Zb, csr, gcnt, out, N, NB);
}

// Round 6
// 127.578 us; speedup vs baseline: 1.8020x; 1.1324x over previous
//
#include <hip/hip_runtime.h>
#include <hip/hip_bf16.h>

#define D       64    // feature dim == units
#define CH      4096  // edges per chunk (bin/stage)
#define BKT     32    // nodes per bucket (aggregate)
#define PASS    1024  // edges staged per pass in aggregate
#define NCOL    16    // reservation-counter colors (chunk & 15)
#define COLMASK 15
#define SCAP    128   // slab capacity per (color,bucket): mean 32, 17-sigma
#define SCAPSH  7     // log2(SCAP)

// ---------------------------------------------------------------------------
// front: blocks [0,NC): per-chunk LDS bucket-sort (R0-K3 body) + ONE global
// atomicAdd per (block,bucket) into COLOR-STRIPED counters gcnt[color*NB+b]
// (color = chunk&15) -> per-address contention depth ~12 instead of 196.
// Blocks [NC,NC+gemmTiles): Z = emb @ W (bf16 out), proven R0 tile.
// rec.x = src(16) | dl(5)<<16 | bkt(11)<<21   (N < 65536, NB < 2048).
// ---------------------------------------------------------------------------
__global__ __launch_bounds__(256) void front(
    const float* __restrict__ emb,
    const float* __restrict__ W,
    __hip_bfloat16* __restrict__ Zb,
    const int*   __restrict__ src,
    const int*   __restrict__ dst,
    const float* __restrict__ w,
    int*         __restrict__ gcnt,   // [NCOL*NB], pre-zeroed by memset
    int2*        __restrict__ csr,    // [NCOL*NB*SCAP] slabs, color-major
    int N, int E, int NB, int NC)
{
    __shared__ int2 rec[CH];       // 32 KB (GEMM branch aliases 16 KB as At)
    __shared__ int  lcnt[1568];    // 6.3 KB
    __shared__ int  sh[256];       // 1 KB

    const int t = threadIdx.x;

    if ((int)blockIdx.x < NC) {
        const int c     = blockIdx.x;
        const int color = c & COLMASK;
        const int e0    = c * CH;
        const int cnt   = min(CH, E - e0);   // multiple of 4 (E%4==0)

        for (int b = t; b < NB; b += 256) lcnt[b] = 0;
        __syncthreads();

        // ---- load + count-with-return (16 edges/thread, vector loads) ----
        int2 myrec[16]; int mypos[16];
        const int4*   s4p = reinterpret_cast<const int4*>(src + e0);
        const int4*   d4p = reinterpret_cast<const int4*>(dst + e0);
        const float4* w4p = reinterpret_cast<const float4*>(w + e0);
#pragma unroll
        for (int i = 0; i < 4; ++i) {
            int g = i * 256 + t;
            if (g * 4 < cnt) {
                int4   s4 = s4p[g];
                int4   d4 = d4p[g];
                float4 w4 = w4p[g];
                int b0 = d4.x >> 5, b1 = d4.y >> 5, b2 = d4.z >> 5, b3 = d4.w >> 5;
                myrec[4*i+0] = make_int2(s4.x | ((d4.x & 31) << 16) | (b0 << 21), __float_as_int(w4.x));
                myrec[4*i+1] = make_int2(s4.y | ((d4.y & 31) << 16) | (b1 << 21), __float_as_int(w4.y));
                myrec[4*i+2] = make_int2(s4.z | ((d4.z & 31) << 16) | (b2 << 21), __float_as_int(w4.z));
                myrec[4*i+3] = make_int2(s4.w | ((d4.w & 31) << 16) | (b3 << 21), __float_as_int(w4.w));
                mypos[4*i+0] = atomicAdd(&lcnt[b0], 1);
                mypos[4*i+1] = atomicAdd(&lcnt[b1], 1);
                mypos[4*i+2] = atomicAdd(&lcnt[b2], 1);
                mypos[4*i+3] = atomicAdd(&lcnt[b3], 1);
            } else {
#pragma unroll
                for (int k = 0; k < 4; ++k) mypos[4*i+k] = -1;
            }
        }
        __syncthreads();

        // ---- per-bucket counts; ISSUE striped reservation atomics early --
        int hv[7], ps[7], gbase[7];
        const int hbase = t * 7;
#pragma unroll
        for (int k = 0; k < 7; ++k) {
            int b = hbase + k;
            hv[k] = (b < NB) ? lcnt[b] : 0;
        }
#pragma unroll
        for (int k = 0; k < 7; ++k)
            gbase[k] = (hv[k] > 0)
                ? atomicAdd(&gcnt[color * NB + hbase + k], hv[k]) : 0;

        // ---- local exclusive scan of counts (for LDS staging layout) -----
        int s = 0;
#pragma unroll
        for (int k = 0; k < 7; ++k) { ps[k] = s; s += hv[k]; }
        sh[t] = s;
        __syncthreads();
        for (int off = 1; off < 256; off <<= 1) {
            int x = (t >= off) ? sh[t - off] : 0;
            __syncthreads();
            sh[t] += x;
            __syncthreads();
        }
        const int hexcl = sh[t] - s;
        __syncthreads();                       // all reads of lcnt done
#pragma unroll
        for (int k = 0; k < 7; ++k) {
            int b = hbase + k;
            if (b < NB) lcnt[b] = hexcl + ps[k];   // localBase
        }
        __syncthreads();

        // ---- stage records sorted by bucket ------------------------------
#pragma unroll
        for (int k = 0; k < 16; ++k) {
            if (mypos[k] >= 0)
                rec[lcnt[(unsigned)myrec[k].x >> 21] + mypos[k]] = myrec[k];
        }
        __syncthreads();

        // ---- lcnt[b] := slabStart(color,b) + gbase - localBase -----------
#pragma unroll
        for (int k = 0; k < 7; ++k) {
            int b = hbase + k;
            if (b < NB)
                lcnt[b] = ((color * NB + b) << SCAPSH) + gbase[k] - (hexcl + ps[k]);
        }
        __syncthreads();

        // ---- bulk write: run of bucket b lands at its reserved slab slot -
        for (int j = t; j < cnt; j += 256) {
            int2 rj = rec[j];
            csr[j + lcnt[(unsigned)rj.x >> 21]] = rj;
        }
        return;
    }

    // ---- GEMM branch: tile (blockIdx.x - NC), proven R0 body --------------
    float* At = (float*)rec;   // 16 KB alias
    const int row0 = ((int)blockIdx.x - NC) * 64;
    const int lane = t & 63;
    const int wave = t >> 6;

    float wcol[D];
#pragma unroll
    for (int k = 0; k < D; ++k) wcol[k] = W[k * D + lane];

    for (int i = t; i < 1024; i += 256) {
        int r = i >> 4, gr = row0 + r;
        float4 v = (gr < N)
            ? reinterpret_cast<const float4*>(emb)[(size_t)gr * 16 + (i & 15)]
            : float4{0.f, 0.f, 0.f, 0.f};
        reinterpret_cast<float4*>(At)[i] = v;
    }
    __syncthreads();

    for (int rr = 0; rr < 16; ++rr) {
        int r = wave * 16 + rr, gr = row0 + r;
        if (gr >= N) break;
        const float4* arow = reinterpret_cast<const float4*>(At + r * D);
        float acc = 0.f;
#pragma unroll
        for (int k4 = 0; k4 < 16; ++k4) {
            float4 a = arow[k4];
            acc = fmaf(a.x, wcol[4 * k4 + 0], acc);
            acc = fmaf(a.y, wcol[4 * k4 + 1], acc);
            acc = fmaf(a.z, wcol[4 * k4 + 2], acc);
            acc = fmaf(a.w, wcol[4 * k4 + 3], acc);
        }
        Zb[(size_t)gr * D + lane] = __float2bfloat16(acc);
    }
}

// ---------------------------------------------------------------------------
// aggregate: one block per 32-node bucket.  Bucket b's edges live in NCOL
// sub-slabs csr[((k*NB+b)<<SCAPSH) .. +gcnt[k*NB+b]).  Build the 17-entry
// prefix in LDS, then segmented load into the SAME verified pass body
// (LDS sort by node + register gather with 3-deep per-slot prefetch).
// ---------------------------------------------------------------------------
__global__ __launch_bounds__(256) void aggregate(
    const __hip_bfloat16* __restrict__ Zb,
    const int2* __restrict__ csr,
    const int*  __restrict__ gcnt,
    float*      __restrict__ out,
    int N, int NB)
{
    __shared__ int2 srec[PASS];   // 8 KB
    __shared__ int  hist[BKT];
    __shared__ int  nbase[BKT + 1];
    __shared__ int  cpre[NCOL + 1];

    const int t = threadIdx.x;
    const int b = blockIdx.x;

    if (t == 0) {
        int s = 0;
#pragma unroll
        for (int k = 0; k < NCOL; ++k) { cpre[k] = s; s += gcnt[k * NB + b]; }
        cpre[NCOL] = s;
    }
    __syncthreads();
    const int T = cpre[NCOL];

    const int wv = t >> 6, lane = t & 63, slot = lane >> 3, q = lane & 7;
    const int4* Zq = reinterpret_cast<const int4*>(Zb);   // bf16 row = 8 int4

    float4 alo[8], ahi[8];
#pragma unroll
    for (int r = 0; r < 8; ++r) { alo[r] = float4{0,0,0,0}; ahi[r] = float4{0,0,0,0}; }

#define FMA8(LO, HI, WW, ZZ)                                                     \
    do {                                                                         \
        (LO).x = fmaf((WW), __uint_as_float((unsigned)(ZZ).x << 16),        (LO).x); \
        (LO).y = fmaf((WW), __uint_as_float((unsigned)(ZZ).x & 0xFFFF0000u),(LO).y); \
        (LO).z = fmaf((WW), __uint_as_float((unsigned)(ZZ).y << 16),        (LO).z); \
        (LO).w = fmaf((WW), __uint_as_float((unsigned)(ZZ).y & 0xFFFF0000u),(LO).w); \
        (HI).x = fmaf((WW), __uint_as_float((unsigned)(ZZ).z << 16),        (HI).x); \
        (HI).y = fmaf((WW), __uint_as_float((unsigned)(ZZ).z & 0xFFFF0000u),(HI).y); \
        (HI).z = fmaf((WW), __uint_as_float((unsigned)(ZZ).w << 16),        (HI).z); \
        (HI).w = fmaf((WW), __uint_as_float((unsigned)(ZZ).w & 0xFFFF0000u),(HI).w); \
    } while (0)

    for (int cur = 0; cur < T; cur += PASS) {
        const int cnt = min(PASS, T - cur);
        if (t < BKT) hist[t] = 0;
        __syncthreads();

        int2 myrec[4]; int mypos[4];
#pragma unroll
        for (int k = 0; k < 4; ++k) {
            int j = k * 256 + t;
            if (j < cnt) {
                int vj = cur + j;
                int kk = 0;
#pragma unroll
                for (int m = 1; m < NCOL; ++m) kk += (vj >= cpre[m]);
                int2 r2 = csr[((kk * NB + b) << SCAPSH) + (vj - cpre[kk])];
                myrec[k] = r2;
                mypos[k] = atomicAdd(&hist[(r2.x >> 16) & (BKT - 1)], 1);
            } else mypos[k] = -1;
        }
        __syncthreads();

        if (t < BKT) {
            int v = hist[t], x = v;
            for (int off = 1; off < BKT; off <<= 1) {
                int y = __shfl_up(x, off, 64);
                if (t >= off) x += y;
            }
            nbase[t] = x - v;
            if (t == BKT - 1) nbase[BKT] = x;
        }
        __syncthreads();

#pragma unroll
        for (int k = 0; k < 4; ++k) {
            if (mypos[k] >= 0)
                srec[nbase[(myrec[k].x >> 16) & (BKT - 1)] + mypos[k]] = myrec[k];
        }
        __syncthreads();

        // gather: wave wv owns nodes [wv*8, wv*8+8), 3-deep prefetched
        for (int r = 0; r < 8; ++r) {
            const int nl = wv * 8 + r;
            const int jb = nbase[nl] + slot;
            const int je = nbase[nl + 1];
            const int j1 = jb + 8, j2 = jb + 16;
            int2 e0 = make_int2(0, 0), e1 = make_int2(0, 0), e2 = make_int2(0, 0);
            if (jb < je) e0 = srec[jb];
            if (j1 < je) e1 = srec[j1];
            if (j2 < je) e2 = srec[j2];
            int4 z0 = make_int4(0,0,0,0), z1 = make_int4(0,0,0,0), z2 = make_int4(0,0,0,0);
            if (jb < je) z0 = Zq[(size_t)(e0.x & 0xFFFF) * 8 + q];
            if (j1 < je) z1 = Zq[(size_t)(e1.x & 0xFFFF) * 8 + q];
            if (j2 < je) z2 = Zq[(size_t)(e2.x & 0xFFFF) * 8 + q];
            FMA8(alo[r], ahi[r], __int_as_float(e0.y), z0);
            FMA8(alo[r], ahi[r], __int_as_float(e1.y), z1);
            FMA8(alo[r], ahi[r], __int_as_float(e2.y), z2);
            for (int j = j2 + 8; j < je; j += 8) {    // tail (deg > 24)
                int2 e = srec[j];
                int4 zz = Zq[(size_t)(e.x & 0xFFFF) * 8 + q];
                FMA8(alo[r], ahi[r], __int_as_float(e.y), zz);
            }
        }
        __syncthreads();
    }

    // reduce the 8 slots + store (8 lanes x 32 B = coalesced 256 B row)
    const int node0 = b * BKT + wv * 8;
#pragma unroll
    for (int r = 0; r < 8; ++r) {
        float4 lo = alo[r], hi = ahi[r];
#pragma unroll
        for (int off = 32; off >= 8; off >>= 1) {
            lo.x += __shfl_down(lo.x, off, 64);
            lo.y += __shfl_down(lo.y, off, 64);
            lo.z += __shfl_down(lo.z, off, 64);
            lo.w += __shfl_down(lo.w, off, 64);
            hi.x += __shfl_down(hi.x, off, 64);
            hi.y += __shfl_down(hi.y, off, 64);
            hi.z += __shfl_down(hi.z, off, 64);
            hi.w += __shfl_down(hi.w, off, 64);
        }
        int node = node0 + r;
        if (lane < 8 && node < N) {
            float4 o0, o1;
            o0.x = fmaxf(lo.x, 0.f); o0.y = fmaxf(lo.y, 0.f);
            o0.z = fmaxf(lo.z, 0.f); o0.w = fmaxf(lo.w, 0.f);
            o1.x = fmaxf(hi.x, 0.f); o1.y = fmaxf(hi.y, 0.f);
            o1.z = fmaxf(hi.z, 0.f); o1.w = fmaxf(hi.w, 0.f);
            float4* orow = reinterpret_cast<float4*>(out) + (size_t)node * 16 + lane * 2;
            orow[0] = o0;
            orow[1] = o1;
        }
    }
#undef FMA8
}

// ---------------------------------------------------------------------------
extern "C" void kernel_launch(void* const* d_in, const int* in_sizes, int n_in,
                              void* d_out, int out_size, void* d_ws, size_t ws_size,
                              hipStream_t stream)
{
    const float* emb  = (const float*)d_in[0];  // [N, 64]
    const int*   esrc = (const int*)  d_in[1];  // [E]
    const int*   edst = (const int*)  d_in[2];  // [E]
    const float* ew   = (const float*)d_in[3];  // [E]
    const float* W    = (const float*)d_in[4];  // [64, 64]
    float*       out  = (float*)d_out;          // [N, 64]

    const int N = in_sizes[0] / D;
    const int E = in_sizes[1];

    const int NB        = (N + BKT - 1) / BKT;   // 1563 buckets
    const int NC        = (E + CH - 1) / CH;     // 196 chunks
    const int gemmTiles = (N + 63) / 64;         // 782

    // Workspace (~32 MB), all segments 16 B aligned.
    char* p = (char*)d_ws;
    __hip_bfloat16* Zb = (__hip_bfloat16*)p;  p += (size_t)N * D * 2;        // 6.4 MB
    int*  gcnt = (int*)p;                     p += (size_t)NCOL * ((NB + 3) & ~3) * 4; // 100 KB
    int2* csr  = (int2*)p;                    // NCOL * NB * SCAP * 8 = 25.6 MB

    hipMemsetAsync(gcnt, 0, (size_t)NCOL * NB * sizeof(int), stream);

    front<<<NC + gemmTiles, 256, 0, stream>>>(
        emb, W, Zb, esrc, edst, ew, gcnt, csr, N, E, NB, NC);

    aggregate<<<NB, 256, 0, stream>>>(
        Zb, csr, gcnt, out, N, NB);
}